// Round 7
// baseline (595.586 us; speedup 1.0000x reference)
//
#include <hip/hip_runtime.h>
#include <hip/hip_bf16.h>

typedef unsigned short u16;
typedef unsigned int   u32;
typedef __bf16 bf16x8 __attribute__((ext_vector_type(8)));
typedef float  f32x4  __attribute__((ext_vector_type(4)));
typedef u32    u32x2  __attribute__((ext_vector_type(2)));

#define KPAD 1088
#define SEQ  1104          // padded float2 slots per sequence (zmap2 max = 1098)
#define PI_F 3.14159265358979323846f
#define WAVE_FENCE() asm volatile("s_waitcnt lgkmcnt(0)" ::: "memory")

__device__ __forceinline__ u16 f2bf(float f){
    u32 u = __float_as_uint(f);
    return (u16)((u + 0x7FFFu + ((u >> 16) & 1u)) >> 16);
}
__device__ __forceinline__ float bf2f(u16 v){ return __uint_as_float(((u32)v) << 16); }
// pad: slot = e + (e>>4) + 4*(e>>8). injective on [0,1024); jv (bit8-9) shifts banks by 8.
__device__ __forceinline__ int zmap2(int e){ return e + (e >> 4) + 4*(e >> 8); }

// natural spectral index k -> physical LDS slot after the in-place 3-step FFT
__device__ __forceinline__ int sig(int k){
    k &= 1023;
    int a = (k >> 6) + (((k >> 2) & 15) << 4) + ((k & 3) << 8);
    return zmap2(a);
}

__device__ __forceinline__ float2 cmul(float2 a, float2 b){
    return make_float2(a.x*b.x - a.y*b.y, a.x*b.y + a.y*b.x);
}
__device__ __forceinline__ void fft4v(float2& x0, float2& x1, float2& x2, float2& x3){
    float2 t0 = make_float2(x0.x+x2.x, x0.y+x2.y);
    float2 t1 = make_float2(x0.x-x2.x, x0.y-x2.y);
    float2 t2 = make_float2(x1.x+x3.x, x1.y+x3.y);
    float2 t3 = make_float2(x1.x-x3.x, x1.y-x3.y);
    x0 = make_float2(t0.x+t2.x, t0.y+t2.y);
    x2 = make_float2(t0.x-t2.x, t0.y-t2.y);
    x1 = make_float2(t1.x+t3.y, t1.y-t3.x);
    x3 = make_float2(t1.x-t3.y, t1.y+t3.x);
}
// 16-point DFT, output X[j] at slot tau(j)=((j&3)<<2)|(j>>2)
__device__ __forceinline__ void fft16(float2 a[16]){
    #pragma unroll
    for (int u1 = 0; u1 < 4; ++u1) fft4v(a[u1], a[u1+4], a[u1+8], a[u1+12]);
    const float Cq = 0.70710678118654752f;
    const float c1 = 0.92387953251128674f, s1 = 0.38268343236508977f;
    a[5]  = cmul(a[5],  make_float2(c1, -s1));
    a[6]  = cmul(a[6],  make_float2(Cq, -Cq));
    a[7]  = cmul(a[7],  make_float2(s1, -c1));
    a[9]  = cmul(a[9],  make_float2(Cq, -Cq));
    a[10] = cmul(a[10], make_float2(0.0f, -1.0f));
    a[11] = cmul(a[11], make_float2(-Cq, -Cq));
    a[13] = cmul(a[13], make_float2(s1, -c1));
    a[14] = cmul(a[14], make_float2(-Cq, -Cq));
    a[15] = cmul(a[15], make_float2(-c1, s1));
    #pragma unroll
    for (int ja = 0; ja < 4; ++ja) fft4v(a[4*ja], a[4*ja+1], a[4*ja+2], a[4*ja+3]);
}

// ---- wave-local FFT phases: wave w operates only on Z = Zs + w*SEQ ----
__device__ __forceinline__ void fft_stepB_wave(float2* Z, int lane){
    int nA = lane & 15, jv = lane >> 4;
    float2 a[16];
    #pragma unroll
    for (int u = 0; u < 16; ++u) a[u] = Z[zmap2(nA + 16*u + 256*jv)];
    fft16(a);
    float s_, c_;
    __sincosf(-2.0f*PI_F*(float)(nA*jv)*(1.0f/1024.0f), &s_, &c_);
    float2 tw = make_float2(c_, s_);
    __sincosf(-2.0f*PI_F*(float)nA*(1.0f/256.0f), &s_, &c_);
    float2 st = make_float2(c_, s_);
    #pragma unroll
    for (int ju = 0; ju < 16; ++ju){
        Z[zmap2(nA + 16*ju + 256*jv)] = cmul(a[((ju&3)<<2)|(ju>>2)], tw);
        tw = cmul(tw, st);
    }
}
__device__ __forceinline__ void fft_stepC_wave(float2* Z, int lane){
    int ju = (lane & 63) >> 2, jv = lane & 3;
    float2 a[16];
    #pragma unroll
    for (int nA = 0; nA < 16; ++nA) a[nA] = Z[zmap2(nA + 16*ju + 256*jv)];
    fft16(a);
    #pragma unroll
    for (int kO = 0; kO < 16; ++kO)
        Z[zmap2(kO + 16*ju + 256*jv)] = a[((kO&3)<<2)|(kO>>2)];
}

// ---------------- weight prep ----------------
__global__ __launch_bounds__(256) void prep_w(const float* __restrict__ w1,
                                              const float* __restrict__ w2,
                                              u16* __restrict__ WSW){
    int gid = blockIdx.x * 256 + threadIdx.x;
    int qd = gid >> 12;
    int t  = qd & 1;
    int n  = (qd >> 1) & 7;
    int l  = qd >> 4;
    int rr = gid & 4095;
    int o  = rr >> 6;
    int k  = rr & 63;
    const float* w = l ? w2 : w1;
    WSW[gid] = f2bf(w[((size_t)(t*8 + n)*64 + k)*64 + o]);
}

// Spectrum layout: S[SIDX * KPAD + k], SIDX = (((b*8+c)*8+n)*2+pl)*64 + p_local

__device__ __forceinline__ u16 unpack_one(const float2* Zc, int k, int pl, float sf){
    float2 Zk = Zc[sig(k)], Zm = Zc[sig(1024 - k)];
    float sn_, cs_; __sincosf(PI_F*(float)k*(1.0f/1024.0f), &sn_, &cs_);
    float Er=0.5f*(Zk.x+Zm.x), Ei=0.5f*(Zk.y-Zm.y);
    float Dr=0.5f*(Zk.x-Zm.x), Di=0.5f*(Zk.y+Zm.y);
    float Xr = Er + cs_*Di - sn_*Dr;
    float Xi = Ei - sn_*Di - cs_*Dr;
    return f2bf((pl ? Xi : Xr) * sf);
}

// Round-7 decomposition (both FFT kernels): one block = ALL 8 channels of one
// (b, p). Previously a block held 4 channels of (p, c0) -> each 32B OUT/X
// sector (the 8 channels of one (l,p)) was split 16B/16B across two blocks,
// giving the measured ~1.7x HBM write amplification (230MB vs 134MB ideal).
// Now every 32B sector is read/written entirely by one block. 512 thr, 8
// waves, LDS 8*SEQ (70.7KB) -> 2 blocks/CU x 8 waves = 16 waves/CU (same
// occupancy as the old 4x4). p-swizzle puts the (2m,2m+1) p-pair sharing a
// 64B line on the SAME XCD (blk and blk+256; 256%8==0).

// ---------------- forward rfft(2048) ----------------
__global__ __launch_bounds__(512) void fwd_fft(const float* __restrict__ X,
                                               u16* __restrict__ S){
    __shared__ float2 Zs[8*SEQ];
    int tid = threadIdx.x;
    int blk = blockIdx.x;
    int b = blk >> 9;
    int p = 2*(blk & 255) + ((blk >> 8) & 1);
    int n  = p >> 6, pl_ = p & 63;
    int wave = tid >> 6, lane = tid & 63;
    int th = tid & 255, half = tid >> 8;   // half: channels 0..3 vs 4..7

    // fused load + pack + step A (registers), write to LDS
    float2 zz[4][4];   // [v][s]; channel = half*4 + s
    #pragma unroll
    for (int v = 0; v < 4; ++v){
        int pi = th + 256*v;
        size_t base = ((size_t)(b*2048 + 2*pi)*512 + p)*8 + half*4;
        f32x4 ve = *(const f32x4*)(X + base);
        f32x4 vo = *(const f32x4*)(X + base + 4096);
        #pragma unroll
        for (int s = 0; s < 4; ++s) zz[v][s] = make_float2(ve[s], vo[s]);
    }
    {
        int u = (th >> 4) & 15;
        float s_, c_;
        __sincosf(-2.0f*PI_F*(float)u*(1.0f/64.0f), &s_, &c_);
        float2 tw1 = make_float2(c_, s_);
        float2 tw2 = cmul(tw1, tw1);
        float2 tw3 = cmul(tw2, tw1);
        #pragma unroll
        for (int s = 0; s < 4; ++s){
            float2 x0 = zz[0][s], x1 = zz[1][s], x2 = zz[2][s], x3 = zz[3][s];
            fft4v(x0, x1, x2, x3);
            float2* Z = Zs + (half*4 + s)*SEQ;
            Z[zmap2(th)]     = x0;
            Z[zmap2(th+256)] = cmul(x1, tw1);
            Z[zmap2(th+512)] = cmul(x2, tw2);
            Z[zmap2(th+768)] = cmul(x3, tw3);
        }
    }
    __syncthreads();                 // only cross-wave handoff in this kernel
    float2* Z = Zs + wave*SEQ;       // wave w owns channel w from here on
    fft_stepB_wave(Z, lane);
    WAVE_FENCE();
    fft_stepC_wave(Z, lane);
    WAVE_FENCE();
    // unpack + coalesced store: wave w = channel w, pl = lane>>5
    const float sf = 0.02209708691207961f;     // 1/sqrt(2048)
    int pl = lane >> 5, tr = lane & 31;
    u16* rp = S + (size_t)((((b*8 + wave)*8 + n)*2 + pl)*64 + pl_)*KPAD;
    for (int kk = tr*2; kk <= 1024; kk += 64){
        u16 w0 = unpack_one(Z, kk, pl, sf);
        if (kk < 1024){
            u16 w1 = unpack_one(Z, kk+1, pl, sf);
            *(u32*)(rp + kk) = (u32)w0 | ((u32)w1 << 16);
        } else {
            rp[kk] = w0;
        }
    }
}

// ---------------- MLP (round-2 proven structure) ----------------
__device__ __forceinline__ bf16x8 fetchB(const u16* mat, int o64, int k64, bool neg){
    const u32x2* pb = (const u32x2*)(mat + o64*68 + k64);
    u32x2 lo = pb[0], hi = pb[1];
    union { u32 u[4]; bf16x8 v; } bt;
    bt.u[0]=lo.x; bt.u[1]=lo.y; bt.u[2]=hi.x; bt.u[3]=hi.y;
    if (neg){ bt.u[0]^=0x80008000u; bt.u[1]^=0x80008000u; bt.u[2]^=0x80008000u; bt.u[3]^=0x80008000u; }
    return bt.v;
}
__device__ __forceinline__ bf16x8 loadU16x8(const u16* pp){
    union { u32 u[4]; bf16x8 v; } t;
    const u32* qq = (const u32*)pp;
    t.u[0]=qq[0]; t.u[1]=qq[1]; t.u[2]=qq[2]; t.u[3]=qq[3];
    return t.v;
}

__global__ __launch_bounds__(256) void mlp_kernel(const u16* __restrict__ WSW,
                                                  const float* __restrict__ b1,
                                                  const float* __restrict__ b2,
                                                  u16* __restrict__ S){
    __shared__ __align__(16) u16 AT[4][64*68];
    __shared__ __align__(16) u16 AS[8448];
    int tid = threadIdx.x;
    int blk = blockIdx.x;
    int n = blk & 7;
    int rest = blk >> 3;               // [0,544) = 32 bc x 17 tiles
    int t17 = rest % 17;
    int bc  = rest / 17;
    int b = bc >> 3, c = bc & 7;
    int k0 = t17 << 6;
    int lane = tid & 63, wv = tid >> 6;
    int lane15 = lane & 15, quad = lane >> 4;

    for (int mi = 0; mi < 4; ++mi){
        const u32* src = (const u32*)(WSW + (size_t)(((mi>>1)*8 + n)*2 + (mi&1))*4096);
        u32* dstm = (u32*)AT[mi];
        for (int d = tid; d < 2048; d += 256){
            int o = d >> 5, kk2 = d & 31;
            dstm[o*34 + kk2] = src[d];
        }
    }
    float bb1[8], bb2v[8];
    #pragma unroll
    for (int nb = 0; nb < 8; ++nb){
        int col = nb*16 + lane15;
        int tt = col >> 6, cc = col & 63;
        bb1[nb]  = b1[tt*512 + n*64 + cc];
        bb2v[nb] = b2[tt*512 + n*64 + cc];
    }
    size_t SB = (size_t)(((b*8 + c)*8 + n)*2)*64;
    {
        int rsub = tid & 31;
        for (int rr = tid >> 5; rr < 128; rr += 8){
            const u16* rp = S + (SB + rr)*KPAD + k0;
            u32 w = *(const u32*)(rp + 2*rsub);
            AS[(2*rsub)*132 + rr]   = (u16)(w & 0xFFFFu);
            AS[(2*rsub+1)*132 + rr] = (u16)(w >> 16);
        }
    }
    __syncthreads();
    // ---- layer 1 ----
    const u16* arow = AS + (wv*16 + lane15)*132;
    bf16x8 afr[4];
    #pragma unroll
    for (int kb = 0; kb < 4; ++kb)
        afr[kb] = loadU16x8(arow + kb*32 + quad*8);
    f32x4 acc[8];
    #pragma unroll
    for (int nb = 0; nb < 8; ++nb){ acc[nb][0]=bb1[nb]; acc[nb][1]=bb1[nb]; acc[nb][2]=bb1[nb]; acc[nb][3]=bb1[nb]; }
    #pragma unroll
    for (int nb = 0; nb < 8; ++nb){
        int o64 = (nb&3)*16 + lane15;
        #pragma unroll
        for (int kb = 0; kb < 4; ++kb){
            int k64 = (kb&1)*32 + quad*8;
            const u16* mat; bool neg = false;
            if (kb < 2) mat = (nb<4) ? AT[0] : AT[1];
            else { if (nb<4){ mat = AT[1]; neg = true; } else mat = AT[0]; }
            acc[nb] = __builtin_amdgcn_mfma_f32_16x16x32_bf16(afr[kb], fetchB(mat,o64,k64,neg), acc[nb], 0,0,0);
        }
    }
    #pragma unroll
    for (int nb = 0; nb < 8; ++nb){
        #pragma unroll
        for (int r4 = 0; r4 < 4; ++r4){
            float xv = acc[nb][r4];
            float u_ = xv * 0.70710678118f;
            float u2 = u_*u_;
            float pg = 1.0f + u2*(-0.333333333f + u2*(0.1f + u2*(-0.0238095238f)));
            float h  = 0.5f * xv * (1.0f + 1.12837916709551f * u_ * pg);
            AS[(wv*16 + quad*4 + r4)*132 + nb*16 + lane15] = f2bf(h);
        }
    }
    // ---- layer 2 ----
    bf16x8 a2[4];
    #pragma unroll
    for (int kb = 0; kb < 4; ++kb)
        a2[kb] = loadU16x8(arow + kb*32 + quad*8);
    f32x4 acc2[8];
    #pragma unroll
    for (int nb = 0; nb < 8; ++nb){ acc2[nb][0]=bb2v[nb]; acc2[nb][1]=bb2v[nb]; acc2[nb][2]=bb2v[nb]; acc2[nb][3]=bb2v[nb]; }
    #pragma unroll
    for (int nb = 0; nb < 8; ++nb){
        int o64 = (nb&3)*16 + lane15;
        #pragma unroll
        for (int kb = 0; kb < 4; ++kb){
            int k64 = (kb&1)*32 + quad*8;
            const u16* mat; bool neg = false;
            if (kb < 2) mat = (nb<4) ? AT[2] : AT[3];
            else { if (nb<4){ mat = AT[3]; neg = true; } else mat = AT[2]; }
            acc2[nb] = __builtin_amdgcn_mfma_f32_16x16x32_bf16(a2[kb], fetchB(mat,o64,k64,neg), acc2[nb], 0,0,0);
        }
    }
    __syncthreads();
    #pragma unroll
    for (int nb = 0; nb < 8; ++nb){
        #pragma unroll
        for (int r4 = 0; r4 < 4; ++r4)
            AS[(nb*16 + lane15)*66 + (wv*16 + quad*4 + r4)] = f2bf(acc2[nb][r4]);
    }
    __syncthreads();
    {
        int rsub = tid & 31;
        int k = k0 + 2*rsub;
        for (int rr = tid >> 5; rr < 128; rr += 8){
            u32 val = *(const u32*)(AS + rr*66 + 2*rsub);
            u16* rp = S + (SB + rr)*KPAD + k0;
            if (k + 1 <= 1024)  *(u32*)(rp + 2*rsub) = val;
            else if (k == 1024) rp[2*rsub] = (u16)(val & 0xFFFFu);
        }
    }
}

// ---------------- inverse irfft(2048) + residual ----------------
// Front end per wave = round-6 proven structure (odd-half LDS stash, 52 VGPR,
// no spills). New: 8 waves = 8 channels of one (b,p); gather writes full 32B
// sectors (8 channels per (l,p)) from a single block.
__global__ __launch_bounds__(512) void inv_fft(const u16* __restrict__ S,
                                               const float* __restrict__ X,
                                               float* __restrict__ OUT){
    __shared__ float2 Zs[8*SEQ];
    int tid = threadIdx.x;
    int blk = blockIdx.x;
    int b = blk >> 9;
    int p = 2*(blk & 255) + ((blk >> 8) & 1);
    int n  = p >> 6, pl_ = p & 63;
    int wave = tid >> 6, lane = tid & 63;

    float2* Z = Zs + wave*SEQ;

    // ---- p1: spectrum -> packed registers (channel = wave) ----
    const u16* rpR = S + (size_t)((((b*8 + wave)*8 + n)*2 + 0)*64 + pl_)*KPAD;
    const u16* rpI = rpR + (size_t)64*KPAD;
    u32 wR[8], wI[8];
    #pragma unroll
    for (int i = 0; i < 8; ++i){
        wR[i] = *(const u32*)(rpR + 2*lane + 128*i);
        wI[i] = *(const u32*)(rpI + 2*lane + 128*i);
    }
    u16 nyq = rpR[1024];               // wave-uniform; only lane 0 consumes it

    // ---- p1.5: stash odd halves into this lane's odd stepA-output slots ----
    #pragma unroll
    for (int i = 0; i < 8; ++i){
        u32 od = (wR[i] >> 16) | (wI[i] & 0xFFFF0000u);
        Z[zmap2(2*lane + 1 + 128*(i&1) + 256*(i>>1))].x = __uint_as_float(od);
    }

    // ---- p2: even unpack + hermitian combine; wR/wI die at the unpack ----
    float er[8], ei[8];
    #pragma unroll
    for (int i = 0; i < 8; ++i){
        er[i] = bf2f((u16)(wR[i] & 0xFFFFu));
        ei[i] = bf2f((u16)(wI[i] & 0xFFFFu));
    }
    if (lane == 0) ei[0] = 0.0f;       // Im Y[0] ignored (matches reference irfft)
    {
        float emr[8], emi[8];
        int srcE = (64 - lane) & 63;
        #pragma unroll
        for (int i = 0; i < 8; ++i){
            emr[i] = __shfl(er[7-i], srcE);
            emi[i] = __shfl(ei[7-i], srcE);
        }
        if (lane == 0){                // lane 0 mirrors in-lane: reg 8-i, reg8 = Nyquist
            emr[0] = bf2f(nyq); emi[0] = 0.0f;
            #pragma unroll
            for (int i = 1; i < 8; ++i){ emr[i] = er[8-i]; emi[i] = ei[8-i]; }
        }
        #pragma unroll
        for (int i = 0; i < 8; ++i){
            float s2_, c2_;
            __sincosf(PI_F*(float)(2*lane + 128*i)*(1.0f/1024.0f), &s2_, &c2_);
            float Ex = 0.5f*(er[i] + emr[i]), Ey = 0.5f*(ei[i] - emi[i]);
            float Dx = 0.5f*(er[i] - emr[i]), Dy = 0.5f*(ei[i] + emi[i]);
            float Ox = c2_*Dx - s2_*Dy,      Oy = c2_*Dy + s2_*Dx;
            er[i] = Ex - Oy;  ei[i] = Ey + Ox;
        }
    }

    // ---- p3: stepA twiddles + even quads -> LDS ----
    float2 twa1, twa2, twa3, twb1, twb2, twb3;
    {
        int u0 = lane >> 3;            // q=2l(+1): u=(q>>4)&15 = l>>3 ; q+128: u+8
        float su_, cu_;
        __sincosf(-2.0f*PI_F*(float)u0*(1.0f/64.0f), &su_, &cu_);
        twa1 = make_float2(cu_, su_);
        twa2 = cmul(twa1, twa1);
        twa3 = cmul(twa2, twa1);
        const float RH = 0.70710678118654752f;
        float2 rot = make_float2(RH, -RH);       // e^{-i*2pi*8/64}
        twb1 = cmul(twa1, rot);
        twb2 = cmul(twb1, twb1);
        twb3 = cmul(twb2, twb1);
    }
    #pragma unroll
    for (int j0 = 0; j0 < 2; ++j0){
        float2 t1 = j0 ? twb1 : twa1;
        float2 t2 = j0 ? twb2 : twa2;
        float2 t3 = j0 ? twb3 : twa3;
        int qb = 2*lane + 128*j0;      // elements k = qb + 256t -> reg i = j0 + 2t
        float2 x0 = make_float2(er[j0],   ei[j0]);
        float2 x1 = make_float2(er[j0+2], ei[j0+2]);
        float2 x2 = make_float2(er[j0+4], ei[j0+4]);
        float2 x3 = make_float2(er[j0+6], ei[j0+6]);
        fft4v(x0, x1, x2, x3);
        Z[zmap2(qb)]     = x0;
        Z[zmap2(qb+256)] = cmul(x1, t1);
        Z[zmap2(qb+512)] = cmul(x2, t2);
        Z[zmap2(qb+768)] = cmul(x3, t3);
    }

    // ---- p4: odd readback + hermitian combine ----
    WAVE_FENCE();                      // stash writes definitely complete
    float odr[8], odi[8];
    #pragma unroll
    for (int i = 0; i < 8; ++i){
        u32 od = __float_as_uint(Z[zmap2(2*lane + 1 + 128*(i&1) + 256*(i>>1))].x);
        odr[i] = bf2f((u16)(od & 0xFFFFu));
        odi[i] = bf2f((u16)(od >> 16));
    }
    {
        float emr[8], emi[8];
        int srcO = 63 - lane;          // mirror lane always valid, no special case
        #pragma unroll
        for (int i = 0; i < 8; ++i){
            emr[i] = __shfl(odr[7-i], srcO);
            emi[i] = __shfl(odi[7-i], srcO);
        }
        #pragma unroll
        for (int i = 0; i < 8; ++i){
            float s2_, c2_;
            __sincosf(PI_F*(float)(2*lane + 1 + 128*i)*(1.0f/1024.0f), &s2_, &c2_);
            float Ex = 0.5f*(odr[i] + emr[i]), Ey = 0.5f*(odi[i] - emi[i]);
            float Dx = 0.5f*(odr[i] - emr[i]), Dy = 0.5f*(odi[i] + emi[i]);
            float Ox = c2_*Dx - s2_*Dy,        Oy = c2_*Dy + s2_*Dx;
            odr[i] = Ex - Oy;  odi[i] = Ey + Ox;
        }
    }

    // ---- p5: stepA odd quads -> LDS (overwrites the stash slots) ----
    #pragma unroll
    for (int j0 = 0; j0 < 2; ++j0){
        float2 t1 = j0 ? twb1 : twa1;
        float2 t2 = j0 ? twb2 : twa2;
        float2 t3 = j0 ? twb3 : twa3;
        int qb = 2*lane + 1 + 128*j0;
        float2 x0 = make_float2(odr[j0],   odi[j0]);
        float2 x1 = make_float2(odr[j0+2], odi[j0+2]);
        float2 x2 = make_float2(odr[j0+4], odi[j0+4]);
        float2 x3 = make_float2(odr[j0+6], odi[j0+6]);
        fft4v(x0, x1, x2, x3);
        Z[zmap2(qb)]     = x0;
        Z[zmap2(qb+256)] = cmul(x1, t1);
        Z[zmap2(qb+512)] = cmul(x2, t2);
        Z[zmap2(qb+768)] = cmul(x3, t3);
    }

    WAVE_FENCE();
    fft_stepB_wave(Z, lane);
    WAVE_FENCE();
    fft_stepC_wave(Z, lane);

    // ---- p6: residual-X load; latency hides under barrier + gather ----
    // thread covers (l=2pi, 2pi+1) x ALL 8 channels: full 32B sectors.
    __builtin_amdgcn_sched_barrier(0);  // don't hoist into stepB/stepC (a[16] live there)
    f32x4 xel[2], xeh[2], xol[2], xoh[2];
    #pragma unroll
    for (int i = 0; i < 2; ++i){
        int pi = tid + 512*i;
        size_t base = ((size_t)(b*2048 + 2*pi)*512 + p)*8;
        xel[i] = *(const f32x4*)(X + base);
        xeh[i] = *(const f32x4*)(X + base + 4);
        xol[i] = *(const f32x4*)(X + base + 4096);
        xoh[i] = *(const f32x4*)(X + base + 4100);
    }

    __syncthreads();                 // only cross-wave handoff: final gather reads all 8 seqs
    // unpack (index reversal) + residual + full-sector float4 stores
    const float sc = 0.04419417382415922f;   // sqrt(2048)/1024
    #pragma unroll
    for (int i = 0; i < 2; ++i){
        int pi = tid + 512*i;
        int zb = sig(1024 - pi);
        size_t base = ((size_t)(b*2048 + 2*pi)*512 + p)*8;
        f32x4 oel, oeh, ool, ooh;
        #pragma unroll
        for (int s = 0; s < 4; ++s){
            float2 r0 = Zs[s*SEQ + zb];
            float2 r1 = Zs[(s+4)*SEQ + zb];
            oel[s] = r0.x*sc + xel[i][s];
            oeh[s] = r1.x*sc + xeh[i][s];
            ool[s] = r0.y*sc + xol[i][s];
            ooh[s] = r1.y*sc + xoh[i][s];
        }
        *(f32x4*)(OUT + base)        = oel;
        *(f32x4*)(OUT + base + 4)    = oeh;
        *(f32x4*)(OUT + base + 4096) = ool;
        *(f32x4*)(OUT + base + 4100) = ooh;
    }
}

extern "C" void kernel_launch(void* const* d_in, const int* in_sizes, int n_in,
                              void* d_out, int out_size, void* d_ws, size_t ws_size,
                              hipStream_t stream){
    (void)in_sizes; (void)n_in; (void)out_size; (void)ws_size;
    const float* x  = (const float*)d_in[0];
    const float* w1 = (const float*)d_in[1];
    const float* b1 = (const float*)d_in[2];
    const float* w2 = (const float*)d_in[3];
    const float* b2 = (const float*)d_in[4];
    float* out = (float*)d_out;
    u16* WSW = (u16*)d_ws;
    u16* S1  = (u16*)((char*)d_ws + (1 << 20));

    prep_w<<<dim3(512),  dim3(256), 0, stream>>>(w1, w2, WSW);
    fwd_fft<<<dim3(2048), dim3(512), 0, stream>>>(x, S1);
    mlp_kernel<<<dim3(4352), dim3(256), 0, stream>>>(WSW, b1, b2, S1);
    inv_fft<<<dim3(2048), dim3(512), 0, stream>>>(S1, x, out);
}

// Round 8
// 450.394 us; speedup vs baseline: 1.3224x; 1.3224x over previous
//
#include <hip/hip_runtime.h>
#include <hip/hip_bf16.h>

typedef unsigned short u16;
typedef unsigned int   u32;
typedef __bf16 bf16x8 __attribute__((ext_vector_type(8)));
typedef float  f32x4  __attribute__((ext_vector_type(4)));
typedef u32    u32x2  __attribute__((ext_vector_type(2)));

#define KPAD 1088
#define SEQ  1104          // padded float2 slots per sequence (zmap2 max = 1098)
#define PI_F 3.14159265358979323846f
#define WAVE_FENCE() asm volatile("s_waitcnt lgkmcnt(0)" ::: "memory")

__device__ __forceinline__ u16 f2bf(float f){
    u32 u = __float_as_uint(f);
    return (u16)((u + 0x7FFFu + ((u >> 16) & 1u)) >> 16);
}
__device__ __forceinline__ float bf2f(u16 v){ return __uint_as_float(((u32)v) << 16); }
// pad: slot = e + (e>>4) + 4*(e>>8). injective on [0,1024); jv (bit8-9) shifts banks by 8.
__device__ __forceinline__ int zmap2(int e){ return e + (e >> 4) + 4*(e >> 8); }

// natural spectral index k -> physical LDS slot after the in-place 3-step FFT
__device__ __forceinline__ int sig(int k){
    k &= 1023;
    int a = (k >> 6) + (((k >> 2) & 15) << 4) + ((k & 3) << 8);
    return zmap2(a);
}

// Round-8 block->p map (both FFT kernels): the 4 blocks covering one 128B
// region of an X/OUT row (p-group 4m..4m+3, 32B per p) must be co-resident on
// the SAME XCD, else each fetches the line separately (round-7: p-pair on
// consecutive blk -> different XCDs -> fwd FETCH 501MB = 3.7x ideal).
// Here siblings sit at blk stride {0,8,16,24}: same XCD (blk%8), dispatched
// within 24 IDs -> co-resident; each 128B line fetched once per XCD.
// p = 4*(xcd + 8*g) + r with xcd=blk&7, g=(blk>>5)&15, r=(blk>>3)&3. Bijective.
__device__ __forceinline__ int pmap(int blk5){
    return 4*((blk5 & 7) + 8*((blk5 >> 5) & 15)) + ((blk5 >> 3) & 3);
}

__device__ __forceinline__ float2 cmul(float2 a, float2 b){
    return make_float2(a.x*b.x - a.y*b.y, a.x*b.y + a.y*b.x);
}
__device__ __forceinline__ void fft4v(float2& x0, float2& x1, float2& x2, float2& x3){
    float2 t0 = make_float2(x0.x+x2.x, x0.y+x2.y);
    float2 t1 = make_float2(x0.x-x2.x, x0.y-x2.y);
    float2 t2 = make_float2(x1.x+x3.x, x1.y+x3.y);
    float2 t3 = make_float2(x1.x-x3.x, x1.y-x3.y);
    x0 = make_float2(t0.x+t2.x, t0.y+t2.y);
    x2 = make_float2(t0.x-t2.x, t0.y-t2.y);
    x1 = make_float2(t1.x+t3.y, t1.y-t3.x);
    x3 = make_float2(t1.x-t3.y, t1.y+t3.x);
}
// 16-point DFT, output X[j] at slot tau(j)=((j&3)<<2)|(j>>2)
__device__ __forceinline__ void fft16(float2 a[16]){
    #pragma unroll
    for (int u1 = 0; u1 < 4; ++u1) fft4v(a[u1], a[u1+4], a[u1+8], a[u1+12]);
    const float Cq = 0.70710678118654752f;
    const float c1 = 0.92387953251128674f, s1 = 0.38268343236508977f;
    a[5]  = cmul(a[5],  make_float2(c1, -s1));
    a[6]  = cmul(a[6],  make_float2(Cq, -Cq));
    a[7]  = cmul(a[7],  make_float2(s1, -c1));
    a[9]  = cmul(a[9],  make_float2(Cq, -Cq));
    a[10] = cmul(a[10], make_float2(0.0f, -1.0f));
    a[11] = cmul(a[11], make_float2(-Cq, -Cq));
    a[13] = cmul(a[13], make_float2(s1, -c1));
    a[14] = cmul(a[14], make_float2(-Cq, -Cq));
    a[15] = cmul(a[15], make_float2(-c1, s1));
    #pragma unroll
    for (int ja = 0; ja < 4; ++ja) fft4v(a[4*ja], a[4*ja+1], a[4*ja+2], a[4*ja+3]);
}

// ---- wave-local FFT phases: wave w operates only on Z = Zs + w*SEQ ----
__device__ __forceinline__ void fft_stepB_wave(float2* Z, int lane){
    int nA = lane & 15, jv = lane >> 4;
    float2 a[16];
    #pragma unroll
    for (int u = 0; u < 16; ++u) a[u] = Z[zmap2(nA + 16*u + 256*jv)];
    fft16(a);
    float s_, c_;
    __sincosf(-2.0f*PI_F*(float)(nA*jv)*(1.0f/1024.0f), &s_, &c_);
    float2 tw = make_float2(c_, s_);
    __sincosf(-2.0f*PI_F*(float)nA*(1.0f/256.0f), &s_, &c_);
    float2 st = make_float2(c_, s_);
    #pragma unroll
    for (int ju = 0; ju < 16; ++ju){
        Z[zmap2(nA + 16*ju + 256*jv)] = cmul(a[((ju&3)<<2)|(ju>>2)], tw);
        tw = cmul(tw, st);
    }
}
__device__ __forceinline__ void fft_stepC_wave(float2* Z, int lane){
    int ju = (lane & 63) >> 2, jv = lane & 3;
    float2 a[16];
    #pragma unroll
    for (int nA = 0; nA < 16; ++nA) a[nA] = Z[zmap2(nA + 16*ju + 256*jv)];
    fft16(a);
    #pragma unroll
    for (int kO = 0; kO < 16; ++kO)
        Z[zmap2(kO + 16*ju + 256*jv)] = a[((kO&3)<<2)|(kO>>2)];
}

// ---------------- weight prep ----------------
__global__ __launch_bounds__(256) void prep_w(const float* __restrict__ w1,
                                              const float* __restrict__ w2,
                                              u16* __restrict__ WSW){
    int gid = blockIdx.x * 256 + threadIdx.x;
    int qd = gid >> 12;
    int t  = qd & 1;
    int n  = (qd >> 1) & 7;
    int l  = qd >> 4;
    int rr = gid & 4095;
    int o  = rr >> 6;
    int k  = rr & 63;
    const float* w = l ? w2 : w1;
    WSW[gid] = f2bf(w[((size_t)(t*8 + n)*64 + k)*64 + o]);
}

// Spectrum layout: S[SIDX * KPAD + k], SIDX = (((b*8+c)*8+n)*2+pl)*64 + p_local

__device__ __forceinline__ u16 unpack_one(const float2* Zc, int k, int pl, float sf){
    float2 Zk = Zc[sig(k)], Zm = Zc[sig(1024 - k)];
    float sn_, cs_; __sincosf(PI_F*(float)k*(1.0f/1024.0f), &sn_, &cs_);
    float Er=0.5f*(Zk.x+Zm.x), Ei=0.5f*(Zk.y-Zm.y);
    float Dr=0.5f*(Zk.x-Zm.x), Di=0.5f*(Zk.y+Zm.y);
    float Xr = Er + cs_*Di - sn_*Dr;
    float Xi = Ei - sn_*Di - cs_*Dr;
    return f2bf((pl ? Xi : Xr) * sf);
}

// ---------------- forward rfft(2048) ----------------
// One block = all 8 channels of one (b,p): 512 thr, 8 waves, LDS 8*SEQ.
__global__ __launch_bounds__(512) void fwd_fft(const float* __restrict__ X,
                                               u16* __restrict__ S){
    __shared__ float2 Zs[8*SEQ];
    int tid = threadIdx.x;
    int blk = blockIdx.x;
    int b = blk >> 9;
    int p = pmap(blk & 511);
    int n  = p >> 6, pl_ = p & 63;
    int wave = tid >> 6, lane = tid & 63;
    int th = tid & 255, half = tid >> 8;   // half: channels 0..3 vs 4..7

    // fused load + pack + step A (registers), write to LDS
    float2 zz[4][4];   // [v][s]; channel = half*4 + s
    #pragma unroll
    for (int v = 0; v < 4; ++v){
        int pi = th + 256*v;
        size_t base = ((size_t)(b*2048 + 2*pi)*512 + p)*8 + half*4;
        f32x4 ve = *(const f32x4*)(X + base);
        f32x4 vo = *(const f32x4*)(X + base + 4096);
        #pragma unroll
        for (int s = 0; s < 4; ++s) zz[v][s] = make_float2(ve[s], vo[s]);
    }
    {
        int u = (th >> 4) & 15;
        float s_, c_;
        __sincosf(-2.0f*PI_F*(float)u*(1.0f/64.0f), &s_, &c_);
        float2 tw1 = make_float2(c_, s_);
        float2 tw2 = cmul(tw1, tw1);
        float2 tw3 = cmul(tw2, tw1);
        #pragma unroll
        for (int s = 0; s < 4; ++s){
            float2 x0 = zz[0][s], x1 = zz[1][s], x2 = zz[2][s], x3 = zz[3][s];
            fft4v(x0, x1, x2, x3);
            float2* Z = Zs + (half*4 + s)*SEQ;
            Z[zmap2(th)]     = x0;
            Z[zmap2(th+256)] = cmul(x1, tw1);
            Z[zmap2(th+512)] = cmul(x2, tw2);
            Z[zmap2(th+768)] = cmul(x3, tw3);
        }
    }
    __syncthreads();                 // only cross-wave handoff in this kernel
    float2* Z = Zs + wave*SEQ;       // wave w owns channel w from here on
    fft_stepB_wave(Z, lane);
    WAVE_FENCE();
    fft_stepC_wave(Z, lane);
    WAVE_FENCE();
    // unpack + coalesced store: wave w = channel w, pl = lane>>5
    const float sf = 0.02209708691207961f;     // 1/sqrt(2048)
    int pl = lane >> 5, tr = lane & 31;
    u16* rp = S + (size_t)((((b*8 + wave)*8 + n)*2 + pl)*64 + pl_)*KPAD;
    for (int kk = tr*2; kk <= 1024; kk += 64){
        u16 w0 = unpack_one(Z, kk, pl, sf);
        if (kk < 1024){
            u16 w1 = unpack_one(Z, kk+1, pl, sf);
            *(u32*)(rp + kk) = (u32)w0 | ((u32)w1 << 16);
        } else {
            rp[kk] = w0;
        }
    }
}

// ---------------- MLP (round-2 proven structure) ----------------
__device__ __forceinline__ bf16x8 fetchB(const u16* mat, int o64, int k64, bool neg){
    const u32x2* pb = (const u32x2*)(mat + o64*68 + k64);
    u32x2 lo = pb[0], hi = pb[1];
    union { u32 u[4]; bf16x8 v; } bt;
    bt.u[0]=lo.x; bt.u[1]=lo.y; bt.u[2]=hi.x; bt.u[3]=hi.y;
    if (neg){ bt.u[0]^=0x80008000u; bt.u[1]^=0x80008000u; bt.u[2]^=0x80008000u; bt.u[3]^=0x80008000u; }
    return bt.v;
}
__device__ __forceinline__ bf16x8 loadU16x8(const u16* pp){
    union { u32 u[4]; bf16x8 v; } t;
    const u32* qq = (const u32*)pp;
    t.u[0]=qq[0]; t.u[1]=qq[1]; t.u[2]=qq[2]; t.u[3]=qq[3];
    return t.v;
}

__global__ __launch_bounds__(256) void mlp_kernel(const u16* __restrict__ WSW,
                                                  const float* __restrict__ b1,
                                                  const float* __restrict__ b2,
                                                  u16* __restrict__ S){
    __shared__ __align__(16) u16 AT[4][64*68];
    __shared__ __align__(16) u16 AS[8448];
    int tid = threadIdx.x;
    int blk = blockIdx.x;
    int n = blk & 7;
    int rest = blk >> 3;               // [0,544) = 32 bc x 17 tiles
    int t17 = rest % 17;
    int bc  = rest / 17;
    int b = bc >> 3, c = bc & 7;
    int k0 = t17 << 6;
    int lane = tid & 63, wv = tid >> 6;
    int lane15 = lane & 15, quad = lane >> 4;

    for (int mi = 0; mi < 4; ++mi){
        const u32* src = (const u32*)(WSW + (size_t)(((mi>>1)*8 + n)*2 + (mi&1))*4096);
        u32* dstm = (u32*)AT[mi];
        for (int d = tid; d < 2048; d += 256){
            int o = d >> 5, kk2 = d & 31;
            dstm[o*34 + kk2] = src[d];
        }
    }
    float bb1[8], bb2v[8];
    #pragma unroll
    for (int nb = 0; nb < 8; ++nb){
        int col = nb*16 + lane15;
        int tt = col >> 6, cc = col & 63;
        bb1[nb]  = b1[tt*512 + n*64 + cc];
        bb2v[nb] = b2[tt*512 + n*64 + cc];
    }
    size_t SB = (size_t)(((b*8 + c)*8 + n)*2)*64;
    {
        int rsub = tid & 31;
        for (int rr = tid >> 5; rr < 128; rr += 8){
            const u16* rp = S + (SB + rr)*KPAD + k0;
            u32 w = *(const u32*)(rp + 2*rsub);
            AS[(2*rsub)*132 + rr]   = (u16)(w & 0xFFFFu);
            AS[(2*rsub+1)*132 + rr] = (u16)(w >> 16);
        }
    }
    __syncthreads();
    // ---- layer 1 ----
    const u16* arow = AS + (wv*16 + lane15)*132;
    bf16x8 afr[4];
    #pragma unroll
    for (int kb = 0; kb < 4; ++kb)
        afr[kb] = loadU16x8(arow + kb*32 + quad*8);
    f32x4 acc[8];
    #pragma unroll
    for (int nb = 0; nb < 8; ++nb){ acc[nb][0]=bb1[nb]; acc[nb][1]=bb1[nb]; acc[nb][2]=bb1[nb]; acc[nb][3]=bb1[nb]; }
    #pragma unroll
    for (int nb = 0; nb < 8; ++nb){
        int o64 = (nb&3)*16 + lane15;
        #pragma unroll
        for (int kb = 0; kb < 4; ++kb){
            int k64 = (kb&1)*32 + quad*8;
            const u16* mat; bool neg = false;
            if (kb < 2) mat = (nb<4) ? AT[0] : AT[1];
            else { if (nb<4){ mat = AT[1]; neg = true; } else mat = AT[0]; }
            acc[nb] = __builtin_amdgcn_mfma_f32_16x16x32_bf16(afr[kb], fetchB(mat,o64,k64,neg), acc[nb], 0,0,0);
        }
    }
    #pragma unroll
    for (int nb = 0; nb < 8; ++nb){
        #pragma unroll
        for (int r4 = 0; r4 < 4; ++r4){
            float xv = acc[nb][r4];
            float u_ = xv * 0.70710678118f;
            float u2 = u_*u_;
            float pg = 1.0f + u2*(-0.333333333f + u2*(0.1f + u2*(-0.0238095238f)));
            float h  = 0.5f * xv * (1.0f + 1.12837916709551f * u_ * pg);
            AS[(wv*16 + quad*4 + r4)*132 + nb*16 + lane15] = f2bf(h);
        }
    }
    // ---- layer 2 ----
    bf16x8 a2[4];
    #pragma unroll
    for (int kb = 0; kb < 4; ++kb)
        a2[kb] = loadU16x8(arow + kb*32 + quad*8);
    f32x4 acc2[8];
    #pragma unroll
    for (int nb = 0; nb < 8; ++nb){ acc2[nb][0]=bb2v[nb]; acc2[nb][1]=bb2v[nb]; acc2[nb][2]=bb2v[nb]; acc2[nb][3]=bb2v[nb]; }
    #pragma unroll
    for (int nb = 0; nb < 8; ++nb){
        int o64 = (nb&3)*16 + lane15;
        #pragma unroll
        for (int kb = 0; kb < 4; ++kb){
            int k64 = (kb&1)*32 + quad*8;
            const u16* mat; bool neg = false;
            if (kb < 2) mat = (nb<4) ? AT[2] : AT[3];
            else { if (nb<4){ mat = AT[3]; neg = true; } else mat = AT[2]; }
            acc2[nb] = __builtin_amdgcn_mfma_f32_16x16x32_bf16(a2[kb], fetchB(mat,o64,k64,neg), acc2[nb], 0,0,0);
        }
    }
    __syncthreads();
    #pragma unroll
    for (int nb = 0; nb < 8; ++nb){
        #pragma unroll
        for (int r4 = 0; r4 < 4; ++r4)
            AS[(nb*16 + lane15)*66 + (wv*16 + quad*4 + r4)] = f2bf(acc2[nb][r4]);
    }
    __syncthreads();
    {
        int rsub = tid & 31;
        int k = k0 + 2*rsub;
        for (int rr = tid >> 5; rr < 128; rr += 8){
            u32 val = *(const u32*)(AS + rr*66 + 2*rsub);
            u16* rp = S + (SB + rr)*KPAD + k0;
            if (k + 1 <= 1024)  *(u32*)(rp + 2*rsub) = val;
            else if (k == 1024) rp[2*rsub] = (u16)(val & 0xFFFFu);
        }
    }
}

// ---------------- inverse irfft(2048) + residual ----------------
// Front end per wave = round-6 proven structure (odd-half LDS stash, 52 VGPR,
// no spills). 8 waves = 8 channels of one (b,p); gather writes full 32B
// sectors; pmap keeps the 4 blocks per 128B line on one XCD.
__global__ __launch_bounds__(512) void inv_fft(const u16* __restrict__ S,
                                               const float* __restrict__ X,
                                               float* __restrict__ OUT){
    __shared__ float2 Zs[8*SEQ];
    int tid = threadIdx.x;
    int blk = blockIdx.x;
    int b = blk >> 9;
    int p = pmap(blk & 511);
    int n  = p >> 6, pl_ = p & 63;
    int wave = tid >> 6, lane = tid & 63;

    float2* Z = Zs + wave*SEQ;

    // ---- p1: spectrum -> packed registers (channel = wave) ----
    const u16* rpR = S + (size_t)((((b*8 + wave)*8 + n)*2 + 0)*64 + pl_)*KPAD;
    const u16* rpI = rpR + (size_t)64*KPAD;
    u32 wR[8], wI[8];
    #pragma unroll
    for (int i = 0; i < 8; ++i){
        wR[i] = *(const u32*)(rpR + 2*lane + 128*i);
        wI[i] = *(const u32*)(rpI + 2*lane + 128*i);
    }
    u16 nyq = rpR[1024];               // wave-uniform; only lane 0 consumes it

    // ---- p1.5: stash odd halves into this lane's odd stepA-output slots ----
    #pragma unroll
    for (int i = 0; i < 8; ++i){
        u32 od = (wR[i] >> 16) | (wI[i] & 0xFFFF0000u);
        Z[zmap2(2*lane + 1 + 128*(i&1) + 256*(i>>1))].x = __uint_as_float(od);
    }

    // ---- p2: even unpack + hermitian combine; wR/wI die at the unpack ----
    float er[8], ei[8];
    #pragma unroll
    for (int i = 0; i < 8; ++i){
        er[i] = bf2f((u16)(wR[i] & 0xFFFFu));
        ei[i] = bf2f((u16)(wI[i] & 0xFFFFu));
    }
    if (lane == 0) ei[0] = 0.0f;       // Im Y[0] ignored (matches reference irfft)
    {
        float emr[8], emi[8];
        int srcE = (64 - lane) & 63;
        #pragma unroll
        for (int i = 0; i < 8; ++i){
            emr[i] = __shfl(er[7-i], srcE);
            emi[i] = __shfl(ei[7-i], srcE);
        }
        if (lane == 0){                // lane 0 mirrors in-lane: reg 8-i, reg8 = Nyquist
            emr[0] = bf2f(nyq); emi[0] = 0.0f;
            #pragma unroll
            for (int i = 1; i < 8; ++i){ emr[i] = er[8-i]; emi[i] = ei[8-i]; }
        }
        #pragma unroll
        for (int i = 0; i < 8; ++i){
            float s2_, c2_;
            __sincosf(PI_F*(float)(2*lane + 128*i)*(1.0f/1024.0f), &s2_, &c2_);
            float Ex = 0.5f*(er[i] + emr[i]), Ey = 0.5f*(ei[i] - emi[i]);
            float Dx = 0.5f*(er[i] - emr[i]), Dy = 0.5f*(ei[i] + emi[i]);
            float Ox = c2_*Dx - s2_*Dy,      Oy = c2_*Dy + s2_*Dx;
            er[i] = Ex - Oy;  ei[i] = Ey + Ox;
        }
    }

    // ---- p3: stepA twiddles + even quads -> LDS ----
    float2 twa1, twa2, twa3, twb1, twb2, twb3;
    {
        int u0 = lane >> 3;            // q=2l(+1): u=(q>>4)&15 = l>>3 ; q+128: u+8
        float su_, cu_;
        __sincosf(-2.0f*PI_F*(float)u0*(1.0f/64.0f), &su_, &cu_);
        twa1 = make_float2(cu_, su_);
        twa2 = cmul(twa1, twa1);
        twa3 = cmul(twa2, twa1);
        const float RH = 0.70710678118654752f;
        float2 rot = make_float2(RH, -RH);       // e^{-i*2pi*8/64}
        twb1 = cmul(twa1, rot);
        twb2 = cmul(twb1, twb1);
        twb3 = cmul(twb2, twb1);
    }
    #pragma unroll
    for (int j0 = 0; j0 < 2; ++j0){
        float2 t1 = j0 ? twb1 : twa1;
        float2 t2 = j0 ? twb2 : twa2;
        float2 t3 = j0 ? twb3 : twa3;
        int qb = 2*lane + 128*j0;      // elements k = qb + 256t -> reg i = j0 + 2t
        float2 x0 = make_float2(er[j0],   ei[j0]);
        float2 x1 = make_float2(er[j0+2], ei[j0+2]);
        float2 x2 = make_float2(er[j0+4], ei[j0+4]);
        float2 x3 = make_float2(er[j0+6], ei[j0+6]);
        fft4v(x0, x1, x2, x3);
        Z[zmap2(qb)]     = x0;
        Z[zmap2(qb+256)] = cmul(x1, t1);
        Z[zmap2(qb+512)] = cmul(x2, t2);
        Z[zmap2(qb+768)] = cmul(x3, t3);
    }

    // ---- p4: odd readback + hermitian combine ----
    WAVE_FENCE();                      // stash writes definitely complete
    float odr[8], odi[8];
    #pragma unroll
    for (int i = 0; i < 8; ++i){
        u32 od = __float_as_uint(Z[zmap2(2*lane + 1 + 128*(i&1) + 256*(i>>1))].x);
        odr[i] = bf2f((u16)(od & 0xFFFFu));
        odi[i] = bf2f((u16)(od >> 16));
    }
    {
        float emr[8], emi[8];
        int srcO = 63 - lane;          // mirror lane always valid, no special case
        #pragma unroll
        for (int i = 0; i < 8; ++i){
            emr[i] = __shfl(odr[7-i], srcO);
            emi[i] = __shfl(odi[7-i], srcO);
        }
        #pragma unroll
        for (int i = 0; i < 8; ++i){
            float s2_, c2_;
            __sincosf(PI_F*(float)(2*lane + 1 + 128*i)*(1.0f/1024.0f), &s2_, &c2_);
            float Ex = 0.5f*(odr[i] + emr[i]), Ey = 0.5f*(odi[i] - emi[i]);
            float Dx = 0.5f*(odr[i] - emr[i]), Dy = 0.5f*(odi[i] + emi[i]);
            float Ox = c2_*Dx - s2_*Dy,        Oy = c2_*Dy + s2_*Dx;
            odr[i] = Ex - Oy;  odi[i] = Ey + Ox;
        }
    }

    // ---- p5: stepA odd quads -> LDS (overwrites the stash slots) ----
    #pragma unroll
    for (int j0 = 0; j0 < 2; ++j0){
        float2 t1 = j0 ? twb1 : twa1;
        float2 t2 = j0 ? twb2 : twa2;
        float2 t3 = j0 ? twb3 : twa3;
        int qb = 2*lane + 1 + 128*j0;
        float2 x0 = make_float2(odr[j0],   odi[j0]);
        float2 x1 = make_float2(odr[j0+2], odi[j0+2]);
        float2 x2 = make_float2(odr[j0+4], odi[j0+4]);
        float2 x3 = make_float2(odr[j0+6], odi[j0+6]);
        fft4v(x0, x1, x2, x3);
        Z[zmap2(qb)]     = x0;
        Z[zmap2(qb+256)] = cmul(x1, t1);
        Z[zmap2(qb+512)] = cmul(x2, t2);
        Z[zmap2(qb+768)] = cmul(x3, t3);
    }

    WAVE_FENCE();
    fft_stepB_wave(Z, lane);
    WAVE_FENCE();
    fft_stepC_wave(Z, lane);

    // ---- p6: residual-X load; latency hides under barrier + gather ----
    // thread covers (l=2pi, 2pi+1) x ALL 8 channels: full 32B sectors.
    __builtin_amdgcn_sched_barrier(0);  // don't hoist into stepB/stepC (a[16] live there)
    f32x4 xel[2], xeh[2], xol[2], xoh[2];
    #pragma unroll
    for (int i = 0; i < 2; ++i){
        int pi = tid + 512*i;
        size_t base = ((size_t)(b*2048 + 2*pi)*512 + p)*8;
        xel[i] = *(const f32x4*)(X + base);
        xeh[i] = *(const f32x4*)(X + base + 4);
        xol[i] = *(const f32x4*)(X + base + 4096);
        xoh[i] = *(const f32x4*)(X + base + 4100);
    }

    __syncthreads();                 // only cross-wave handoff: final gather reads all 8 seqs
    // unpack (index reversal) + residual + full-sector float4 stores
    const float sc = 0.04419417382415922f;   // sqrt(2048)/1024
    #pragma unroll
    for (int i = 0; i < 2; ++i){
        int pi = tid + 512*i;
        int zb = sig(1024 - pi);
        size_t base = ((size_t)(b*2048 + 2*pi)*512 + p)*8;
        f32x4 oel, oeh, ool, ooh;
        #pragma unroll
        for (int s = 0; s < 4; ++s){
            float2 r0 = Zs[s*SEQ + zb];
            float2 r1 = Zs[(s+4)*SEQ + zb];
            oel[s] = r0.x*sc + xel[i][s];
            oeh[s] = r1.x*sc + xeh[i][s];
            ool[s] = r0.y*sc + xol[i][s];
            ooh[s] = r1.y*sc + xoh[i][s];
        }
        *(f32x4*)(OUT + base)        = oel;
        *(f32x4*)(OUT + base + 4)    = oeh;
        *(f32x4*)(OUT + base + 4096) = ool;
        *(f32x4*)(OUT + base + 4100) = ooh;
    }
}

extern "C" void kernel_launch(void* const* d_in, const int* in_sizes, int n_in,
                              void* d_out, int out_size, void* d_ws, size_t ws_size,
                              hipStream_t stream){
    (void)in_sizes; (void)n_in; (void)out_size; (void)ws_size;
    const float* x  = (const float*)d_in[0];
    const float* w1 = (const float*)d_in[1];
    const float* b1 = (const float*)d_in[2];
    const float* w2 = (const float*)d_in[3];
    const float* b2 = (const float*)d_in[4];
    float* out = (float*)d_out;
    u16* WSW = (u16*)d_ws;
    u16* S1  = (u16*)((char*)d_ws + (1 << 20));

    prep_w<<<dim3(512),  dim3(256), 0, stream>>>(w1, w2, WSW);
    fwd_fft<<<dim3(2048), dim3(512), 0, stream>>>(x, S1);
    mlp_kernel<<<dim3(4352), dim3(256), 0, stream>>>(WSW, b1, b2, S1);
    inv_fft<<<dim3(2048), dim3(512), 0, stream>>>(S1, x, out);
}